// Round 6
// baseline (229.444 us; speedup 1.0000x reference)
//
#include <hip/hip_runtime.h>

typedef float v2f __attribute__((ext_vector_type(2)));
typedef float v4f __attribute__((ext_vector_type(4)));
typedef __fp16 v2h __attribute__((ext_vector_type(2)));  // matches cvt_pkrtz/fdot2

#define TT 1024
#define NIN 6
#define NN 64
#define CHUNK 32
#define NCHUNK 32
#define SCALE 0.09486832980505137f  // sqrt(2*alpha*sigma_rec^2)

__device__ __forceinline__ v2f pk_fma(v2f a, v2f b, v2f c) {
  return __builtin_elementwise_fma(a, b, c);  // -> v_pk_fma_f32
}

__device__ __forceinline__ v2h h2_from_i(int i) {
  return __builtin_bit_cast(v2h, i);
}
__device__ __forceinline__ int i_from_h2(v2h h) {
  return __builtin_bit_cast(int, h);
}

typedef const __attribute__((address_space(1))) unsigned int gu32;
typedef __attribute__((address_space(3))) unsigned int lu32;

__global__ void __launch_bounds__(64) rnn_scan_kernel(
    const float* __restrict__ u, const float* __restrict__ noise,
    const float* __restrict__ Wrec, const float* __restrict__ Win,
    float* __restrict__ out) {
  const int b = blockIdx.x;
  const int n = threadIdx.x;  // lane owns state component n

  // Recurrence broadcast is IN-REGISTER (readlane of f16 pairs) -- no LDS
  // round trip on the critical path. LDS only stages noise/u chunks and the
  // state history for the chunked store epilogue (both off the serial chain).
  __shared__ __align__(16) float smHist[CHUNK][NN];      // 8 KB
  __shared__ __align__(16) float smNz[2][CHUNK * NN];    // noise chunks (2x8KB)
  __shared__ __align__(16) float smU[2][CHUNK * NIN];    // u chunks (2x768B)

  const float* nzg = noise + (size_t)b * TT * NN;
  const float* ug  = u + (size_t)b * TT * NIN;
  float* outB = out + (size_t)b * TT * NN;

  // ---- stage chunk 0 (latency hidden behind the weight loads below)
#pragma unroll
  for (int i = 0; i < 8; ++i)
    __builtin_amdgcn_global_load_lds((gu32*)(nzg + i * 256 + n * 4),
                                     (lu32*)(&smNz[0][i * 256]), 16, 0, 0);
#pragma unroll
  for (int j = 0; j < 3; ++j)
    __builtin_amdgcn_global_load_lds((gu32*)(ug + j * 64 + n),
                                     (lu32*)(&smU[0][j * 64]), 4, 0, 0);

  // ---- per-lane weights: W_rec row n as 32 f16 pairs (k, k+1), W_in f32.
  v2h w16[NN / 2];
#pragma unroll
  for (int k = 0; k < NN; k += 4) {
    const float4 v = *reinterpret_cast<const float4*>(Wrec + n * NN + k);
    w16[k / 2 + 0] = __builtin_amdgcn_cvt_pkrtz(v.x, v.y);
    w16[k / 2 + 1] = __builtin_amdgcn_cvt_pkrtz(v.z, v.w);
  }
  v2f win2[3];
#pragma unroll
  for (int j = 0; j < 3; ++j)
    win2[j] = v2f{Win[n * NIN + 2 * j + 0], Win[n * NIN + 2 * j + 1]};

  float s = 0.0f;
  int hpk = 0;                  // packed (s[2p], s[2p+1]) f16 pair; s_0 = 0
  smHist[CHUNK - 1][n] = 0.0f;  // (unused value, keeps layout warm)
  outB[n] = 0.0f;               // states[:,0,:] = 0

  // Drain once -> clean vmcnt accounting for the hand-counted waits below.
  asm volatile("s_waitcnt vmcnt(0)" ::: "memory");
  __builtin_amdgcn_sched_barrier(0);

  for (int c = 0; c < NCHUNK; ++c) {
    const int buf = c & 1;

    if (c + 1 < NCHUNK) {
      // prefetch chunk c+1 into the other buffer (consumed 32 steps later)
      const float* ng = nzg + (size_t)(c + 1) * CHUNK * NN;
      const float* gg = ug + (size_t)(c + 1) * CHUNK * NIN;
      float* nl = &smNz[buf ^ 1][0];
      float* ul = &smU[buf ^ 1][0];
#pragma unroll
      for (int i = 0; i < 8; ++i)
        __builtin_amdgcn_global_load_lds((gu32*)(ng + i * 256 + n * 4),
                                         (lu32*)(nl + i * 256), 16, 0, 0);
#pragma unroll
      for (int j = 0; j < 3; ++j)
        __builtin_amdgcn_global_load_lds((gu32*)(gg + j * 64 + n),
                                         (lu32*)(ul + j * 64), 4, 0, 0);
      // Outstanding (oldest->newest): 11 loads(chunk c) + 8 stores(chunk c-1
      // epilogue) + 11 loads(chunk c+1); vmcnt retires in issue order.
      asm volatile("s_waitcnt vmcnt(19)" ::: "memory");
    } else {
      asm volatile("s_waitcnt vmcnt(8)" ::: "memory");
    }
    __builtin_amdgcn_sched_barrier(0);

    const float* nzL = &smNz[buf][0] + n;  // per-lane column
    const float* uL  = &smU[buf][0];       // uniform rows

#pragma unroll 4
    for (int st = 0; st < CHUNK; ++st) {
      // step t = 32c+st: s_{t+1} = 0.8 s + 0.2 relu(W_rec s + W_in u_t + sc*nz)
      // u/noise reads issue at step-top (no deps) -> latency hidden under dots.
      const float nzc = nzL[st * NN];                 // ds_read_b32
      const v2f* u2p = (const v2f*)(uL + st * NIN);   // 3x ds_read_b64 bcast
      v2f uacc = pk_fma(u2p[0], win2[0], v2f{SCALE * nzc, 0.0f});
      uacc = pk_fma(u2p[1], win2[1], uacc);
      uacc = pk_fma(u2p[2], win2[2], uacc);

      // In-register broadcast matvec: pair p=(2p,2p+1) lives packed-f16 in
      // lane 2p's hpk. 8 accumulator chains, batches of 8 rdl then 8 dot2
      // (>=8-instr distance on the SGPR readlane results).
      float a0, a1, a2, a3, a4, a5, a6, a7;
      {
        int r0 = __builtin_amdgcn_readlane(hpk, 0);
        int r1 = __builtin_amdgcn_readlane(hpk, 2);
        int r2 = __builtin_amdgcn_readlane(hpk, 4);
        int r3 = __builtin_amdgcn_readlane(hpk, 6);
        int r4 = __builtin_amdgcn_readlane(hpk, 8);
        int r5 = __builtin_amdgcn_readlane(hpk, 10);
        int r6 = __builtin_amdgcn_readlane(hpk, 12);
        int r7 = __builtin_amdgcn_readlane(hpk, 14);
        a0 = __builtin_amdgcn_fdot2(h2_from_i(r0), w16[0], 0.0f, false);
        a1 = __builtin_amdgcn_fdot2(h2_from_i(r1), w16[1], 0.0f, false);
        a2 = __builtin_amdgcn_fdot2(h2_from_i(r2), w16[2], 0.0f, false);
        a3 = __builtin_amdgcn_fdot2(h2_from_i(r3), w16[3], 0.0f, false);
        a4 = __builtin_amdgcn_fdot2(h2_from_i(r4), w16[4], 0.0f, false);
        a5 = __builtin_amdgcn_fdot2(h2_from_i(r5), w16[5], 0.0f, false);
        a6 = __builtin_amdgcn_fdot2(h2_from_i(r6), w16[6], 0.0f, false);
        a7 = __builtin_amdgcn_fdot2(h2_from_i(r7), w16[7], 0.0f, false);
      }
#pragma unroll
      for (int j = 1; j < 4; ++j) {
        int r0 = __builtin_amdgcn_readlane(hpk, 16 * j + 0);
        int r1 = __builtin_amdgcn_readlane(hpk, 16 * j + 2);
        int r2 = __builtin_amdgcn_readlane(hpk, 16 * j + 4);
        int r3 = __builtin_amdgcn_readlane(hpk, 16 * j + 6);
        int r4 = __builtin_amdgcn_readlane(hpk, 16 * j + 8);
        int r5 = __builtin_amdgcn_readlane(hpk, 16 * j + 10);
        int r6 = __builtin_amdgcn_readlane(hpk, 16 * j + 12);
        int r7 = __builtin_amdgcn_readlane(hpk, 16 * j + 14);
        a0 = __builtin_amdgcn_fdot2(h2_from_i(r0), w16[8 * j + 0], a0, false);
        a1 = __builtin_amdgcn_fdot2(h2_from_i(r1), w16[8 * j + 1], a1, false);
        a2 = __builtin_amdgcn_fdot2(h2_from_i(r2), w16[8 * j + 2], a2, false);
        a3 = __builtin_amdgcn_fdot2(h2_from_i(r3), w16[8 * j + 3], a3, false);
        a4 = __builtin_amdgcn_fdot2(h2_from_i(r4), w16[8 * j + 4], a4, false);
        a5 = __builtin_amdgcn_fdot2(h2_from_i(r5), w16[8 * j + 5], a5, false);
        a6 = __builtin_amdgcn_fdot2(h2_from_i(r6), w16[8 * j + 6], a6, false);
        a7 = __builtin_amdgcn_fdot2(h2_from_i(r7), w16[8 * j + 7], a7, false);
      }

      float pre = ((a0 + a1) + (a2 + a3)) + ((a4 + a5) + (a6 + a7));
      pre += uacc.x + uacc.y;
      const float r = fmaxf(pre, 0.0f);
      s = fmaf(0.2f, r, 0.8f * s);
      smHist[st][n] = s;  // store path only (off the recurrence chain)

      // pack s for next step's broadcast: DPP quad-swap gives lane n the
      // partner s[n^1]; even lane 2p then packs (s[2p], s[2p+1]). Odd lanes
      // pack the wrong order but are never readlane'd.
      const int part = __builtin_amdgcn_update_dpp(
          0, __float_as_int(s), 0xB1 /*quad_perm[1,0,3,2]*/, 0xF, 0xF, false);
      hpk = i_from_h2(__builtin_amdgcn_cvt_pkrtz(s, __int_as_float(part)));
    }

    // ---- chunk epilogue: dump 32 state rows (output rows 32c+1..32c+32).
    v4f st4[8];
    const float* hbase = &smHist[0][0] + (n >> 4) * NN + (n & 15) * 4;
#pragma unroll
    for (int i = 0; i < 8; ++i)
      st4[i] = *(const v4f*)(hbase + i * 4 * NN);       // 8x ds_read_b128

    float* gp = outB + (size_t)(c * CHUNK + 1) * NN + (n >> 4) * NN + (n & 15) * 4;
    if (c + 1 < NCHUNK) {
#pragma unroll
      for (int i = 0; i < 8; ++i)
        *(v4f*)(gp + (size_t)i * 4 * NN) = st4[i];      // 8x store_dwordx4
    } else {
      // last chunk: rows 993..1023 only (row 1024 doesn't exist)
#pragma unroll
      for (int i = 0; i < 7; ++i)
        *(v4f*)(gp + (size_t)i * 4 * NN) = st4[i];
      if (n < 48)  // rows 1021..1023
        *(v4f*)(gp + (size_t)7 * 4 * NN) = st4[7];
    }
  }
}

extern "C" void kernel_launch(void* const* d_in, const int* in_sizes, int n_in,
                              void* d_out, int out_size, void* d_ws, size_t ws_size,
                              hipStream_t stream) {
  const float* u     = (const float*)d_in[0];
  const float* noise = (const float*)d_in[1];
  const float* Wrec  = (const float*)d_in[2];
  const float* Win   = (const float*)d_in[3];
  float* out = (float*)d_out;

  const int B = in_sizes[0] / (TT * NIN);  // 512
  hipLaunchKernelGGL(rnn_scan_kernel, dim3(B), dim3(64), 0, stream,
                     u, noise, Wrec, Win, out);
}